// Round 2
// 389.006 us; speedup vs baseline: 1.2560x; 1.2560x over previous
//
#include <hip/hip_runtime.h>
#include <hip/hip_bf16.h>

// Problem constants
constexpr int Bb = 4, Nn = 1024, Kk = 32;
constexpr int CS = 384, CZ = 128, CH = 16, Hh = 12, PQn = 4, PVn = 8;
constexpr int HC = Hh * CH;            // 192
constexpr int NCOLS = 1152;            // q(192)|k(192)|v(192)|qp(144)|kvp(432)
constexpr int FEAT = 960;              // o(192)|o_pt(288)|dists(96)|o_pair(384)
constexpr int NNODE = Bb * Nn;         // 4096
constexpr int NEDGE = NNODE * Kk;      // 131072
constexpr int ZOC = 44;                // zout cols: bbuf(12) | zd(32)

// Workspace float offsets (flag occupies wsf[0..3])
constexpr int O_WNODE = 4;                           // [384][1152]
constexpr int O_WOUT  = O_WNODE + 384 * 1152;        // [960][384]
constexpr int O_WZP   = O_WOUT + 960 * 384;          // [128][48]  (LN-scale-folded [wb|wdz], zero-padded)
constexpr int O_BVEC  = O_WZP + 128 * 48;            // [48]       (LN-bias term)
constexpr int O_SLN   = O_BVEC + 48;                 // [4096][384]
constexpr int O_P     = O_SLN + NNODE * CS;          // [4096][1152]
constexpr int O_ZOUT  = O_P + NNODE * NCOLS;         // [131072][44]
constexpr int O_FEAT  = O_ZOUT + NEDGE * ZOC;        // [4096][960]
constexpr int O_MR    = O_FEAT;                      // alias: [131072][2] mean/rstd, dead before attn writes FEAT
constexpr int O_TMP   = O_SLN;                       // alias: [2][4096][384] split-K temp, SLN/P dead after attn
constexpr int TOTAL_F = O_FEAT + NNODE * FEAT;       // ~16.8M floats

__device__ __forceinline__ float ldf(const float* p, int i) { return p[i]; }
__device__ __forceinline__ float ldf(const __hip_bfloat16* p, int i) { return __bfloat162float(p[i]); }
__device__ __forceinline__ void stf(float* p, int i, float v) { p[i] = v; }
__device__ __forceinline__ void stf(__hip_bfloat16* p, int i, float v) { p[i] = __float2bfloat16(v); }
__device__ __forceinline__ float4 ld4(const float* p, int i) { return *(const float4*)(p + i); }
__device__ __forceinline__ float4 ld4(const __hip_bfloat16* p, int i) {
    ushort4 u = *(const ushort4*)(p + i);
    return make_float4(__uint_as_float((unsigned)u.x << 16),
                       __uint_as_float((unsigned)u.y << 16),
                       __uint_as_float((unsigned)u.z << 16),
                       __uint_as_float((unsigned)u.w << 16));
}

// Detect input dtype from s_mask (all ones): f32 -> 0x3F800000, bf16x2 -> 0x3F803F80
__global__ void k_detect(const unsigned* smask_raw, int* flag) {
    if (threadIdx.x == 0) *flag = (smask_raw[0] == 0x3F803F80u) ? 1 : 0;
}

// Concat + convert node weights and w_out to f32
template <typename T>
__global__ __launch_bounds__(256) void k_wconv(const T* wq, const T* wk, const T* wv,
                                               const T* wqp, const T* wkvp,
                                               const T* wout, float* wsf,
                                               const int* flag, int want) {
    if (*flag != want) return;
    int idx = blockIdx.x * 256 + threadIdx.x;
    if (idx < 384 * 1152) {
        int row = idx / 1152, col = idx - row * 1152;
        float v;
        if      (col < 192) v = ldf(wq,  row * 192 + col);
        else if (col < 384) v = ldf(wk,  row * 192 + col - 192);
        else if (col < 576) v = ldf(wv,  row * 192 + col - 384);
        else if (col < 720) v = ldf(wqp, row * 144 + col - 576);
        else                v = ldf(wkvp, row * 432 + col - 720);
        wsf[O_WNODE + idx] = v;
    } else if (idx < 384 * 1152 + 960 * 384) {
        int u = idx - 384 * 1152;
        wsf[O_WOUT + u] = ldf(wout, u);
    }
}

// Build W' = diag(ln_z_scale) @ [wb|wdz] padded to 48 cols, and bvec = ln_z_bias @ [wb|wdz]
template <typename T>
__global__ __launch_bounds__(256) void k_wzprep(const T* wb, const T* wdz, const T* zsc, const T* zbi,
                                                float* wzp, float* bvec, const int* flag, int want) {
    if (*flag != want) return;
    int t = threadIdx.x;
    if (t < 128) {
        float sc = ldf(zsc, t);
        for (int o = 0; o < 48; o++) {
            float w = 0.f;
            if (o < 12)      w = ldf(wb, t * 12 + o);
            else if (o < 44) w = ldf(wdz, t * 32 + o - 12);
            wzp[t * 48 + o] = sc * w;
        }
    } else if (t < 128 + 48) {
        int o = t - 128;
        float acc = 0.f;
        if (o < 44)
            for (int c = 0; c < 128; c++)
                acc += ldf(zbi, c) * (o < 12 ? ldf(wb, c * 12 + o) : ldf(wdz, c * 32 + o - 12));
        bvec[o] = acc;
    }
}

// LayerNorm of s rows (384) -> f32
template <typename T>
__global__ __launch_bounds__(384) void k_sln(const T* s, const T* sc, const T* bi,
                                             float* sln, const int* flag, int want) {
    if (*flag != want) return;
    int row = blockIdx.x, t = threadIdx.x;
    float x = ldf(s, row * CS + t);
    float sum = x, sq = x * x;
    #pragma unroll
    for (int m = 32; m; m >>= 1) { sum += __shfl_xor(sum, m, 64); sq += __shfl_xor(sq, m, 64); }
    __shared__ float ssum[6], ssq[6];
    int w = t >> 6;
    if ((t & 63) == 0) { ssum[w] = sum; ssq[w] = sq; }
    __syncthreads();
    if (t == 0) {
        float S = 0, Q = 0;
        for (int i = 0; i < 6; i++) { S += ssum[i]; Q += ssq[i]; }
        ssum[0] = S; ssq[0] = Q;
    }
    __syncthreads();
    float mean = ssum[0] * (1.f / CS);
    float var  = ssq[0] * (1.f / CS) - mean * mean;
    float r = rsqrtf(var + 1e-5f);
    sln[row * CS + t] = (x - mean) * r * ldf(sc, t) + ldf(bi, t);
}

// Per-edge LN stats: mean + rstd
template <typename T>
__global__ __launch_bounds__(256) void k_zstats(const T* z, float* mr, const int* flag, int want) {
    if (*flag != want) return;
    int t = threadIdx.x, r = t >> 5, lane = t & 31;
    int row = blockIdx.x * 8 + r;
    float4 v = ld4(z, row * CZ + lane * 4);
    float sum = v.x + v.y + v.z + v.w;
    float sq  = v.x * v.x + v.y * v.y + v.z * v.z + v.w * v.w;
    #pragma unroll
    for (int m = 16; m; m >>= 1) { sum += __shfl_xor(sum, m, 64); sq += __shfl_xor(sq, m, 64); }
    if (lane == 0) {
        float mean = sum * (1.f / CZ);
        float var  = sq * (1.f / CZ) - mean * mean;
        mr[row * 2]     = mean;
        mr[row * 2 + 1] = rsqrtf(var + 1e-5f);
    }
}

// zout[edge][48>44] = ((z - mean)*rstd) @ W' + bvec   (LN scale/bias folded into W'/bvec)
// 256 edges/block, thread = 4 rows x 12 cols, full 128x48 weight tile in LDS.
template <typename T>
__global__ __launch_bounds__(256) void k_zgemm(const T* z, const float* mr, const float* wzp,
                                               const float* bvec, float* zout,
                                               const int* flag, int want) {
    if (*flag != want) return;
    __shared__ float Ws[128 * 48];
    __shared__ float As[16][260];
    int t = threadIdx.x;
    int edge0 = blockIdx.x * 256;
    for (int i = t; i < 128 * 48; i += 256) Ws[i] = wzp[i];
    int tm = t >> 2, tn = t & 3, col = tn * 12;
    int sr = t >> 2, q = t & 3;
    float mu[4], rs[4];
    #pragma unroll
    for (int u = 0; u < 4; u++) {
        int e = edge0 + sr + 64 * u;
        mu[u] = mr[e * 2]; rs[u] = mr[e * 2 + 1];
    }
    float acc[4][12];
    #pragma unroll
    for (int i = 0; i < 4; i++)
        #pragma unroll
        for (int j = 0; j < 12; j++) acc[i][j] = bvec[col + j];
    for (int kt = 0; kt < CZ; kt += 16) {
        float4 zv[4];
        #pragma unroll
        for (int u = 0; u < 4; u++) zv[u] = ld4(z, (edge0 + sr + 64 * u) * CZ + kt + q * 4);
        __syncthreads();
        #pragma unroll
        for (int u = 0; u < 4; u++) {
            int rr = sr + 64 * u;
            As[q * 4 + 0][rr] = (zv[u].x - mu[u]) * rs[u];
            As[q * 4 + 1][rr] = (zv[u].y - mu[u]) * rs[u];
            As[q * 4 + 2][rr] = (zv[u].z - mu[u]) * rs[u];
            As[q * 4 + 3][rr] = (zv[u].w - mu[u]) * rs[u];
        }
        __syncthreads();
        #pragma unroll
        for (int kk = 0; kk < 16; kk++) {
            float4 a = *(const float4*)&As[kk][tm * 4];
            const float* wr = &Ws[(kt + kk) * 48 + col];
            float4 b0 = *(const float4*)(wr);
            float4 b1 = *(const float4*)(wr + 4);
            float4 b2 = *(const float4*)(wr + 8);
            float av[4]  = {a.x, a.y, a.z, a.w};
            float bv[12] = {b0.x, b0.y, b0.z, b0.w, b1.x, b1.y, b1.z, b1.w, b2.x, b2.y, b2.z, b2.w};
            #pragma unroll
            for (int i = 0; i < 4; i++)
                #pragma unroll
                for (int j = 0; j < 12; j++) acc[i][j] += av[i] * bv[j];
        }
    }
    #pragma unroll
    for (int i = 0; i < 4; i++) {
        int e = edge0 + tm * 4 + i;
        #pragma unroll
        for (int j = 0; j < 12; j++) {
            int c = col + j;
            if (c < ZOC) zout[e * ZOC + c] = acc[i][j];
        }
    }
}

// f32 GEMM: 64x128 tile, 4x8 microtile, b128 LDS fragments, optional split-K over blockIdx.z.
__global__ __launch_bounds__(256) void k_gemm(const float* A, int lda, const float* Bm, int ldb,
                                              float* C, int ldc, int ksplit, int csplit) {
    __shared__ float As[16][68];
    __shared__ float Bs[16][136];
    int t = threadIdx.x;
    int row0 = blockIdx.x * 64, col0 = blockIdx.y * 128;
    int kbeg = blockIdx.z * ksplit, kend = kbeg + ksplit;
    C += (size_t)blockIdx.z * csplit;
    int tx = t & 15, ty = t >> 4;
    int ar = t >> 2, aq = t & 3;
    int bk = t >> 4, bc = (t & 15) * 8;
    float acc[4][8] = {};
    for (int kt = kbeg; kt < kend; kt += 16) {
        float4 a0 = *(const float4*)(A + (row0 + ar) * lda + kt + aq * 4);
        float4 b0 = *(const float4*)(Bm + (kt + bk) * ldb + col0 + bc);
        float4 b1 = *(const float4*)(Bm + (kt + bk) * ldb + col0 + bc + 4);
        __syncthreads();
        As[aq * 4 + 0][ar] = a0.x; As[aq * 4 + 1][ar] = a0.y;
        As[aq * 4 + 2][ar] = a0.z; As[aq * 4 + 3][ar] = a0.w;
        *(float4*)&Bs[bk][bc] = b0;
        *(float4*)&Bs[bk][bc + 4] = b1;
        __syncthreads();
        #pragma unroll
        for (int kk = 0; kk < 16; kk++) {
            float4 av  = *(const float4*)&As[kk][ty * 4];
            float4 blo = *(const float4*)&Bs[kk][tx * 4];
            float4 bhi = *(const float4*)&Bs[kk][64 + tx * 4];
            float aa[4] = {av.x, av.y, av.z, av.w};
            float bb[8] = {blo.x, blo.y, blo.z, blo.w, bhi.x, bhi.y, bhi.z, bhi.w};
            #pragma unroll
            for (int i = 0; i < 4; i++)
                #pragma unroll
                for (int j = 0; j < 8; j++)
                    acc[i][j] += aa[i] * bb[j];
        }
    }
    #pragma unroll
    for (int i = 0; i < 4; i++) {
        float* Cr = C + (size_t)(row0 + ty * 4 + i) * ldc + col0;
        *(float4*)(Cr + tx * 4)      = make_float4(acc[i][0], acc[i][1], acc[i][2], acc[i][3]);
        *(float4*)(Cr + 64 + tx * 4) = make_float4(acc[i][4], acc[i][5], acc[i][6], acc[i][7]);
    }
}

// Reduce 2 split-K slices -> typed output
template <typename TO>
__global__ __launch_bounds__(256) void k_outred(const float* tmp, TO* out, const int* flag, int want) {
    if (*flag != want) return;
    int i = (blockIdx.x * 256 + threadIdx.x) * 4;
    float4 a = *(const float4*)(tmp + i);
    float4 b = *(const float4*)(tmp + NNODE * CS + i);
    stf(out, i,     a.x + b.x); stf(out, i + 1, a.y + b.y);
    stf(out, i + 2, a.z + b.z); stf(out, i + 3, a.w + b.w);
}

// Attention: ONE WAVE PER NODE (4 nodes / 256-thread block), no barriers, all-float4 gathers.
// Per-node LDS (1792 f32): q[0..192) qp[192..336) hw[336..348) Mn[348..357) msk[360..392)
//                          l[392..776) feat[776..1736)
template <typename T>
__global__ __launch_bounds__(256, 4) void k_attn(const float* P, const float* zout,
                                                 const int* eidx, const T* smask, const T* rot,
                                                 const T* hwq, float* featg, const int* flag, int want) {
    if (*flag != want) return;
    __shared__ float nds[4][1792];
    __shared__ int js[4][32];
    int w = threadIdx.x >> 6, lane = threadIdx.x & 63;
    int node = blockIdx.x * 4 + w;
    int b = node >> 10;
    float* S = nds[w];
    int* J = js[w];
    const float* Pn = P + (size_t)node * NCOLS;
    for (int u = lane; u < 336; u += 64)
        S[u] = (u < 192) ? Pn[u] : Pn[384 + u];           // q | q_pts (cols 576..719)
    if (lane < 32) {
        int j = eidx[node * Kk + lane];
        J[lane] = b * Nn + j;
        S[360 + lane] = ldf(smask, node) * ldf(smask, b * Nn + j);
    } else if (lane < 44) {
        int h = lane - 32;
        float x = ldf(hwq, h);
        S[336 + h] = logf(1.f + expf(x)) * 0.13608276348795434f;   // softplus * sqrt(1/54)
    } else if (lane < 53) {
        int u = lane - 44;
        int i = u / 3, jj = u - i * 3;
        float m = 0;
        #pragma unroll
        for (int l = 0; l < 3; l++)
            m += ldf(rot, node * 9 + l * 3 + i) * ldf(rot, node * 9 + l * 3 + jj);
        S[348 + u] = m;                                    // M = R^T R
    }
    __builtin_amdgcn_wave_barrier();
    // logits + softmax: 6 iterations, (h,k) = (2*it + lane>>5, lane&31), l index = lane + 64*it
    #pragma unroll
    for (int it = 0; it < 6; it++) {
        int u = lane + 64 * it;
        int h = u >> 5, k = u & 31;
        const float* Pj = P + (size_t)J[k] * NCOLS;
        float qk = 0;
        const float4* pk4 = (const float4*)(Pj + 192 + h * 16);
        const float4* qs4 = (const float4*)(S + h * 16);
        #pragma unroll
        for (int c4 = 0; c4 < 4; c4++) {
            float4 pv = pk4[c4], qv = qs4[c4];
            qk += qv.x * pv.x + qv.y * pv.y + qv.z * pv.z + qv.w * pv.w;
        }
        float M00 = S[348], M01 = S[349], M02 = S[350],
              M11 = S[352], M12 = S[353], M22 = S[356];
        const float4* pp4 = (const float4*)(Pj + 720 + h * 36);
        const float4* qp4 = (const float4*)(S + 192 + h * 12);
        float4 A0 = pp4[0], A1 = pp4[1], A2 = pp4[2];
        float4 B0 = qp4[0], B1 = qp4[1], B2 = qp4[2];
        float d[12] = {B0.x - A0.x, B0.y - A0.y, B0.z - A0.z, B0.w - A0.w,
                       B1.x - A1.x, B1.y - A1.y, B1.z - A1.z, B1.w - A1.w,
                       B2.x - A2.x, B2.y - A2.y, B2.z - A2.z, B2.w - A2.w};
        float sq = 0;
        #pragma unroll
        for (int p = 0; p < 4; p++) {
            float d0 = d[p * 3], d1 = d[p * 3 + 1], d2 = d[p * 3 + 2];
            sq += M00 * d0 * d0 + M11 * d1 * d1 + M22 * d2 * d2
                + 2.f * (M01 * d0 * d1 + M02 * d0 * d2 + M12 * d1 * d2);
        }
        float logit = qk * 0.14433756729740643f                       // 1/sqrt(48)
                    + 0.5773502691896258f * zout[((size_t)node * Kk + k) * ZOC + h]
                    - 0.5f * S[336 + h] * sq
                    + 1e5f * (S[360 + k] - 1.f);
        float mx = logit;
        #pragma unroll
        for (int m = 16; m; m >>= 1) mx = fmaxf(mx, __shfl_xor(mx, m, 64));
        float e = expf(logit - mx);
        float ssum = e;
        #pragma unroll
        for (int m = 16; m; m >>= 1) ssum += __shfl_xor(ssum, m, 64);
        S[392 + u] = e / ssum;
    }
    __builtin_amdgcn_wave_barrier();
    // accumulation: 216 float4 tasks: o(48) | o_pt raw(72) | o_pair(96)
    for (int u = lane; u < 216; u += 64) {
        int h, off, fbase, pair = 0;
        if (u < 48)       { h = u >> 2; off = 384 + h * 16 + (u & 3) * 4; fbase = h * 16 + (u & 3) * 4; }
        else if (u < 120) { int v = u - 48;  h = v / 6; int q = v - h * 6;
                            off = 732 + h * 36 + q * 4; fbase = 192 + h * 24 + q * 4; }
        else              { int v = u - 120; h = v >> 3;
                            off = 12 + (v & 7) * 4; fbase = 576 + h * 32 + (v & 7) * 4; pair = 1; }
        float4 acc = {0.f, 0.f, 0.f, 0.f};
        const float* lrow = S + 392 + h * 32;
        if (!pair) {
            #pragma unroll 8
            for (int k = 0; k < 32; k++) {
                float lw = lrow[k];
                float4 pv = *(const float4*)(P + (size_t)J[k] * NCOLS + off);
                acc.x += lw * pv.x; acc.y += lw * pv.y; acc.z += lw * pv.z; acc.w += lw * pv.w;
            }
        } else {
            const float* zr = zout + (size_t)node * Kk * ZOC + off;
            #pragma unroll 8
            for (int k = 0; k < 32; k++) {
                float lw = lrow[k];
                float4 pv = *(const float4*)(zr + k * ZOC);
                acc.x += lw * pv.x; acc.y += lw * pv.y; acc.z += lw * pv.z; acc.w += lw * pv.w;
            }
        }
        *(float4*)&S[776 + fbase] = acc;
    }
    __builtin_amdgcn_wave_barrier();
    // apply M to o_pt, compute dists
    for (int u = lane; u < 96; u += 64) {
        float r0 = S[776 + 192 + u * 3 + 0];
        float r1 = S[776 + 192 + u * 3 + 1];
        float r2 = S[776 + 192 + u * 3 + 2];
        float o0 = S[348] * r0 + S[349] * r1 + S[350] * r2;
        float o1 = S[351] * r0 + S[352] * r1 + S[353] * r2;
        float o2 = S[354] * r0 + S[355] * r1 + S[356] * r2;
        S[776 + 192 + u * 3 + 0] = o0;
        S[776 + 192 + u * 3 + 1] = o1;
        S[776 + 192 + u * 3 + 2] = o2;
        S[776 + 480 + u] = sqrtf(o0 * o0 + o1 * o1 + o2 * o2 + 1e-8f);
    }
    __builtin_amdgcn_wave_barrier();
    float* og = featg + (size_t)node * FEAT;
    for (int u = lane; u < 240; u += 64)
        *(float4*)(og + u * 4) = *(const float4*)&S[776 + u * 4];
}

extern "C" void kernel_launch(void* const* d_in, const int* in_sizes, int n_in,
                              void* d_out, int out_size, void* d_ws, size_t ws_size,
                              hipStream_t stream) {
    float* wsf = (float*)d_ws;
    int* flag = (int*)d_ws;
    const void* s = d_in[0];   const void* z = d_in[1];
    const int* eidx = (const int*)d_in[2];
    const void* rot = d_in[3];                         // d_in[4] trans: unused (cancels exactly)
    const void* smask = d_in[5];
    const void* lns_sc = d_in[6]; const void* lns_bi = d_in[7];
    const void* lnz_sc = d_in[8]; const void* lnz_bi = d_in[9];
    const void* wq = d_in[10]; const void* wk = d_in[11]; const void* wv = d_in[12];
    const void* wqp = d_in[13]; const void* wkvp = d_in[14];
    const void* wb = d_in[15]; const void* wdz = d_in[16];
    const void* hwq = d_in[17]; const void* wout = d_in[18];

    k_detect<<<1, 64, 0, stream>>>((const unsigned*)smask, flag);

    constexpr int WCONV_N = (384 * 1152 + 960 * 384) / 256;   // 3168
    k_wconv<float><<<WCONV_N, 256, 0, stream>>>((const float*)wq, (const float*)wk, (const float*)wv,
        (const float*)wqp, (const float*)wkvp, (const float*)wout, wsf, flag, 0);
    k_wconv<__hip_bfloat16><<<WCONV_N, 256, 0, stream>>>((const __hip_bfloat16*)wq,
        (const __hip_bfloat16*)wk, (const __hip_bfloat16*)wv, (const __hip_bfloat16*)wqp,
        (const __hip_bfloat16*)wkvp, (const __hip_bfloat16*)wout, wsf, flag, 1);

    k_wzprep<float><<<1, 256, 0, stream>>>((const float*)wb, (const float*)wdz,
        (const float*)lnz_sc, (const float*)lnz_bi, wsf + O_WZP, wsf + O_BVEC, flag, 0);
    k_wzprep<__hip_bfloat16><<<1, 256, 0, stream>>>((const __hip_bfloat16*)wb, (const __hip_bfloat16*)wdz,
        (const __hip_bfloat16*)lnz_sc, (const __hip_bfloat16*)lnz_bi, wsf + O_WZP, wsf + O_BVEC, flag, 1);

    k_sln<float><<<NNODE, 384, 0, stream>>>((const float*)s, (const float*)lns_sc, (const float*)lns_bi,
                                            wsf + O_SLN, flag, 0);
    k_sln<__hip_bfloat16><<<NNODE, 384, 0, stream>>>((const __hip_bfloat16*)s, (const __hip_bfloat16*)lns_sc,
                                                     (const __hip_bfloat16*)lns_bi, wsf + O_SLN, flag, 1);

    k_zstats<float><<<NEDGE / 8, 256, 0, stream>>>((const float*)z, wsf + O_MR, flag, 0);
    k_zstats<__hip_bfloat16><<<NEDGE / 8, 256, 0, stream>>>((const __hip_bfloat16*)z, wsf + O_MR, flag, 1);

    k_zgemm<float><<<NEDGE / 256, 256, 0, stream>>>((const float*)z, wsf + O_MR, wsf + O_WZP,
        wsf + O_BVEC, wsf + O_ZOUT, flag, 0);
    k_zgemm<__hip_bfloat16><<<NEDGE / 256, 256, 0, stream>>>((const __hip_bfloat16*)z, wsf + O_MR,
        wsf + O_WZP, wsf + O_BVEC, wsf + O_ZOUT, flag, 1);

    // P = s_ln @ [w_q|w_k|w_v|w_q_pts|w_kv_pts]   (f32, dtype-independent)
    k_gemm<<<dim3(NNODE / 64, NCOLS / 128, 1), 256, 0, stream>>>(
        wsf + O_SLN, CS, wsf + O_WNODE, NCOLS, wsf + O_P, NCOLS, CS, 0);

    k_attn<float><<<NNODE / 4, 256, 0, stream>>>(wsf + O_P, wsf + O_ZOUT, eidx,
        (const float*)smask, (const float*)rot, (const float*)hwq, wsf + O_FEAT, flag, 0);
    k_attn<__hip_bfloat16><<<NNODE / 4, 256, 0, stream>>>(wsf + O_P, wsf + O_ZOUT, eidx,
        (const float*)smask == nullptr ? (const __hip_bfloat16*)smask : (const __hip_bfloat16*)smask,
        (const __hip_bfloat16*)rot, (const __hip_bfloat16*)hwq, wsf + O_FEAT, flag, 1);

    // out = feat @ w_out, split-K=2 into f32 temp (dtype-independent), then typed reduce
    k_gemm<<<dim3(NNODE / 64, CS / 128, 2), 256, 0, stream>>>(
        wsf + O_FEAT, FEAT, wsf + O_WOUT, CS, wsf + O_TMP, CS, FEAT / 2, NNODE * CS);
    k_outred<float><<<NNODE * CS / 1024, 256, 0, stream>>>(wsf + O_TMP, (float*)d_out, flag, 0);
    k_outred<__hip_bfloat16><<<NNODE * CS / 1024, 256, 0, stream>>>(wsf + O_TMP,
        (__hip_bfloat16*)d_out, flag, 1);
}

// Round 3
// 376.655 us; speedup vs baseline: 1.2972x; 1.0328x over previous
//
#include <hip/hip_runtime.h>
#include <hip/hip_bf16.h>

// Problem constants
constexpr int Bb = 4, Nn = 1024, Kk = 32;
constexpr int CS = 384, CZ = 128, CH = 16, Hh = 12, PQn = 4, PVn = 8;
constexpr int HC = Hh * CH;            // 192
constexpr int NCOLS = 1152;            // q(192)|k(192)|v(192)|qp(144)|kvp(432)
constexpr int FEAT = 960;              // o(192)|o_pt(288)|dists(96)|o_pair(384)
constexpr int NNODE = Bb * Nn;         // 4096
constexpr int NEDGE = NNODE * Kk;      // 131072
constexpr int ZOC = 44;                // zout cols: bbuf(12) | zd(32)

// Workspace float offsets (flag occupies wsf[0..3])
constexpr int O_WNODE = 4;                           // [384][1152]
constexpr int O_WOUT  = O_WNODE + 384 * 1152;        // [960][384]
constexpr int O_WZP   = O_WOUT + 960 * 384;          // [128][48] LN-scale-folded [wb|wdz], padded
constexpr int O_BVEC  = O_WZP + 128 * 48;            // [48] LN-bias @ W
constexpr int O_CSUM  = O_BVEC + 48;                 // [48] colsum of W'
constexpr int O_SLN   = O_CSUM + 48;                 // [4096][384]
constexpr int O_P     = O_SLN + NNODE * CS;          // [4096][1152]
constexpr int O_ZOUT  = O_P + NNODE * NCOLS;         // [131072][44]
constexpr int O_FEAT  = O_ZOUT + NEDGE * ZOC;        // [4096][960]
constexpr int TOTAL_F = O_FEAT + NNODE * FEAT;       // ~16.4M floats

__device__ __forceinline__ float ldf(const float* p, int i) { return p[i]; }
__device__ __forceinline__ float ldf(const __hip_bfloat16* p, int i) { return __bfloat162float(p[i]); }
__device__ __forceinline__ void stf(float* p, int i, float v) { p[i] = v; }
__device__ __forceinline__ void stf(__hip_bfloat16* p, int i, float v) { p[i] = __float2bfloat16(v); }
__device__ __forceinline__ float4 ld4(const float* p, int i) { return *(const float4*)(p + i); }
__device__ __forceinline__ float4 ld4(const __hip_bfloat16* p, int i) {
    ushort4 u = *(const ushort4*)(p + i);
    return make_float4(__uint_as_float((unsigned)u.x << 16),
                       __uint_as_float((unsigned)u.y << 16),
                       __uint_as_float((unsigned)u.z << 16),
                       __uint_as_float((unsigned)u.w << 16));
}

// Fallback dtype detect from s_mask (all ones): f32 -> 0x3F800000, bf16x2 -> 0x3F803F80
__global__ void k_detect(const unsigned* smask_raw, int* flag) {
    if (threadIdx.x == 0) *flag = (smask_raw[0] == 0x3F803F80u) ? 1 : 0;
}

// Fused prep: blocks [0,2112) weight concat/convert; [2112,6208) s-LayerNorm; 6208 z-weight prep.
template <typename T>
__global__ __launch_bounds__(384) void k_prep(const T* s, const T* lns_sc, const T* lns_bi,
                                              const T* wq, const T* wk, const T* wv,
                                              const T* wqp, const T* wkvp, const T* wout,
                                              const T* wb, const T* wdz, const T* zsc, const T* zbi,
                                              float* wsf, const int* flag, int want) {
    if (flag && *flag != want) return;
    int blk = blockIdx.x, t = threadIdx.x;
    __shared__ float ssum[6], ssq[6];
    if (blk < 2112) {
        int idx = blk * 384 + t;
        if (idx < 384 * 1152) {
            int row = idx / 1152, col = idx - row * 1152;
            float v;
            if      (col < 192) v = ldf(wq,  row * 192 + col);
            else if (col < 384) v = ldf(wk,  row * 192 + col - 192);
            else if (col < 576) v = ldf(wv,  row * 192 + col - 384);
            else if (col < 720) v = ldf(wqp, row * 144 + col - 576);
            else                v = ldf(wkvp, row * 432 + col - 720);
            wsf[O_WNODE + idx] = v;
        } else {
            int u = idx - 384 * 1152;
            wsf[O_WOUT + u] = ldf(wout, u);
        }
    } else if (blk < 2112 + 4096) {
        int row = blk - 2112;
        float x = ldf(s, row * CS + t);
        float sum = x, sq = x * x;
        #pragma unroll
        for (int m = 32; m; m >>= 1) { sum += __shfl_xor(sum, m, 64); sq += __shfl_xor(sq, m, 64); }
        int w = t >> 6;
        if ((t & 63) == 0) { ssum[w] = sum; ssq[w] = sq; }
        __syncthreads();
        if (t == 0) {
            float S = 0, Q = 0;
            for (int i = 0; i < 6; i++) { S += ssum[i]; Q += ssq[i]; }
            ssum[0] = S; ssq[0] = Q;
        }
        __syncthreads();
        float mean = ssum[0] * (1.f / CS);
        float var  = ssq[0] * (1.f / CS) - mean * mean;
        float r = rsqrtf(var + 1e-5f);
        wsf[O_SLN + row * CS + t] = (x - mean) * r * ldf(lns_sc, t) + ldf(lns_bi, t);
    } else {
        if (t < 128) {
            float sc = ldf(zsc, t);
            for (int o = 0; o < 48; o++) {
                float w = 0.f;
                if (o < 12)      w = ldf(wb, t * 12 + o);
                else if (o < 44) w = ldf(wdz, t * 32 + o - 12);
                wsf[O_WZP + t * 48 + o] = sc * w;
            }
        } else if (t < 176) {
            int o = t - 128;
            float acc = 0.f;
            if (o < 44)
                for (int c = 0; c < 128; c++)
                    acc += ldf(zbi, c) * (o < 12 ? ldf(wb, c * 12 + o) : ldf(wdz, c * 32 + o - 12));
            wsf[O_BVEC + o] = acc;
        } else if (t < 224) {
            int o = t - 176;
            float acc = 0.f;
            if (o < 44)
                for (int c = 0; c < 128; c++)
                    acc += ldf(zsc, c) * (o < 12 ? ldf(wb, c * 12 + o) : ldf(wdz, c * 32 + o - 12));
            wsf[O_CSUM + o] = acc;
        }
    }
}

// z-GEMM with fused LN: accumulate RAW z @ W', per-row stats computed in-flight,
// epilogue: zout = rs*acc - rs*mu*csum + bvec.  256 edges/block.
template <typename T>
__global__ __launch_bounds__(256) void k_zg(const T* z, const float* wzp, const float* bvec,
                                            const float* csum, float* zout,
                                            const int* flag, int want) {
    if (flag && *flag != want) return;
    __shared__ float Ws[128 * 48];
    __shared__ float As[16][260];
    __shared__ float mus[256], rss[256];
    int t = threadIdx.x;
    int edge0 = blockIdx.x * 256;
    for (int i = t; i < 128 * 48; i += 256) Ws[i] = wzp[i];
    int tm = t >> 2, tn = t & 3, col = tn * 12;
    int sr = t >> 2, q = t & 3;
    float psum[4] = {}, psq[4] = {};
    float acc[4][12] = {};
    for (int kt = 0; kt < CZ; kt += 16) {
        float4 zv[4];
        #pragma unroll
        for (int u = 0; u < 4; u++) {
            zv[u] = ld4(z, (edge0 + sr + 64 * u) * CZ + kt + q * 4);
            psum[u] += zv[u].x + zv[u].y + zv[u].z + zv[u].w;
            psq[u]  += zv[u].x * zv[u].x + zv[u].y * zv[u].y
                     + zv[u].z * zv[u].z + zv[u].w * zv[u].w;
        }
        __syncthreads();
        #pragma unroll
        for (int u = 0; u < 4; u++) {
            int rr = sr + 64 * u;
            As[q * 4 + 0][rr] = zv[u].x;
            As[q * 4 + 1][rr] = zv[u].y;
            As[q * 4 + 2][rr] = zv[u].z;
            As[q * 4 + 3][rr] = zv[u].w;
        }
        __syncthreads();
        #pragma unroll
        for (int kk = 0; kk < 16; kk++) {
            float4 a = *(const float4*)&As[kk][tm * 4];
            const float* wr = &Ws[(kt + kk) * 48 + col];
            float4 b0 = *(const float4*)(wr);
            float4 b1 = *(const float4*)(wr + 4);
            float4 b2 = *(const float4*)(wr + 8);
            float av[4]  = {a.x, a.y, a.z, a.w};
            float bv[12] = {b0.x, b0.y, b0.z, b0.w, b1.x, b1.y, b1.z, b1.w, b2.x, b2.y, b2.z, b2.w};
            #pragma unroll
            for (int i = 0; i < 4; i++)
                #pragma unroll
                for (int j = 0; j < 12; j++) acc[i][j] += av[i] * bv[j];
        }
        __syncthreads();
    }
    // per-row LN stats: reduce over the 4-lane q-group (adjacent lanes)
    #pragma unroll
    for (int u = 0; u < 4; u++) {
        float s = psum[u], qq = psq[u];
        s += __shfl_xor(s, 1, 64); s += __shfl_xor(s, 2, 64);
        qq += __shfl_xor(qq, 1, 64); qq += __shfl_xor(qq, 2, 64);
        if (q == 0) {
            float mu = s * (1.f / CZ);
            mus[sr + 64 * u] = mu;
            rss[sr + 64 * u] = rsqrtf(qq * (1.f / CZ) - mu * mu + 1e-5f);
        }
    }
    __syncthreads();
    #pragma unroll
    for (int i = 0; i < 4; i++) {
        int r = tm * 4 + i;
        float mu = mus[r], rs = rss[r];
        int e = edge0 + r;
        #pragma unroll
        for (int j = 0; j < 12; j++) {
            int c = col + j;
            if (c < ZOC) zout[(size_t)e * ZOC + c] = rs * acc[i][j] - rs * mu * csum[c] + bvec[c];
        }
    }
}

// f32 GEMM for P: 64x128 tile, 4x8 microtile, b128 LDS fragments.
__global__ __launch_bounds__(256) void k_gemm(const float* A, int lda, const float* Bm, int ldb,
                                              float* C, int ldc, int Kdim) {
    __shared__ float As[16][68];
    __shared__ float Bs[16][136];
    int t = threadIdx.x;
    int row0 = blockIdx.x * 64, col0 = blockIdx.y * 128;
    int tx = t & 15, ty = t >> 4;
    int ar = t >> 2, aq = t & 3;
    int bk = t >> 4, bc = (t & 15) * 8;
    float acc[4][8] = {};
    for (int kt = 0; kt < Kdim; kt += 16) {
        float4 a0 = *(const float4*)(A + (size_t)(row0 + ar) * lda + kt + aq * 4);
        float4 b0 = *(const float4*)(Bm + (size_t)(kt + bk) * ldb + col0 + bc);
        float4 b1 = *(const float4*)(Bm + (size_t)(kt + bk) * ldb + col0 + bc + 4);
        __syncthreads();
        As[aq * 4 + 0][ar] = a0.x; As[aq * 4 + 1][ar] = a0.y;
        As[aq * 4 + 2][ar] = a0.z; As[aq * 4 + 3][ar] = a0.w;
        *(float4*)&Bs[bk][bc] = b0;
        *(float4*)&Bs[bk][bc + 4] = b1;
        __syncthreads();
        #pragma unroll
        for (int kk = 0; kk < 16; kk++) {
            float4 av  = *(const float4*)&As[kk][ty * 4];
            float4 blo = *(const float4*)&Bs[kk][tx * 4];
            float4 bhi = *(const float4*)&Bs[kk][64 + tx * 4];
            float aa[4] = {av.x, av.y, av.z, av.w};
            float bb[8] = {blo.x, blo.y, blo.z, blo.w, bhi.x, bhi.y, bhi.z, bhi.w};
            #pragma unroll
            for (int i = 0; i < 4; i++)
                #pragma unroll
                for (int j = 0; j < 8; j++)
                    acc[i][j] += aa[i] * bb[j];
        }
    }
    #pragma unroll
    for (int i = 0; i < 4; i++) {
        float* Cr = C + (size_t)(row0 + ty * 4 + i) * ldc + col0;
        *(float4*)(Cr + tx * 4)      = make_float4(acc[i][0], acc[i][1], acc[i][2], acc[i][3]);
        *(float4*)(Cr + 64 + tx * 4) = make_float4(acc[i][4], acc[i][5], acc[i][6], acc[i][7]);
    }
}

// out-GEMM: 32x64 tile, 2x4 microtile, single launch (768 blocks), typed C.
template <typename TO>
__global__ __launch_bounds__(256) void k_gout(const float* A, const float* Bm, TO* C,
                                              const int* flag, int want) {
    if (flag && *flag != want) return;
    __shared__ float As[16][36];
    __shared__ float Bs[16][68];
    int t = threadIdx.x;
    int row0 = blockIdx.x * 32, col0 = blockIdx.y * 64;
    int ar = (t >> 2) & 31, aq = t & 3;
    int bk = t >> 4, bc = (t & 15) * 4;
    int ty = t >> 4, tx = t & 15;
    int m0 = ty * 2, n0 = tx * 4;
    float acc[2][4] = {};
    for (int kt = 0; kt < FEAT; kt += 16) {
        float4 av = {};
        if (t < 128) av = *(const float4*)(A + (size_t)(row0 + ar) * FEAT + kt + aq * 4);
        float4 bv = *(const float4*)(Bm + (size_t)(kt + bk) * CS + col0 + bc);
        __syncthreads();
        if (t < 128) {
            As[aq * 4 + 0][ar] = av.x; As[aq * 4 + 1][ar] = av.y;
            As[aq * 4 + 2][ar] = av.z; As[aq * 4 + 3][ar] = av.w;
        }
        *(float4*)&Bs[bk][bc] = bv;
        __syncthreads();
        #pragma unroll
        for (int kk = 0; kk < 16; kk++) {
            float a0 = As[kk][m0], a1 = As[kk][m0 + 1];
            float4 b = *(const float4*)&Bs[kk][n0];
            acc[0][0] += a0 * b.x; acc[0][1] += a0 * b.y; acc[0][2] += a0 * b.z; acc[0][3] += a0 * b.w;
            acc[1][0] += a1 * b.x; acc[1][1] += a1 * b.y; acc[1][2] += a1 * b.z; acc[1][3] += a1 * b.w;
        }
        __syncthreads();
    }
    #pragma unroll
    for (int i = 0; i < 2; i++)
        #pragma unroll
        for (int j = 0; j < 4; j++)
            stf(C, (size_t)(row0 + m0 + i) * CS + col0 + n0 + j, acc[i][j]);
}

// Attention: one wave per node, XCD-chunked block swizzle, stride-33 softmax array.
// Per-node LDS (1760 f32): q[0..192) qp[192..336) hw[336..348) Mn[348..357) msk[360..392)
//                          l[392..788) stride-33 by h | feat[788..1748)
template <typename T>
__global__ __launch_bounds__(256) void k_attn(const float* P, const float* zout,
                                              const int* eidx, const T* smask, const T* rot,
                                              const T* hwq, float* featg, const int* flag, int want) {
    if (flag && *flag != want) return;
    __shared__ float nds[4][1760];
    __shared__ int js[4][32];
    int bid = blockIdx.x;
    int nb = ((bid & 7) << 7) + (bid >> 3);   // XCD-chunked: XCD x owns nodes [x*512,(x+1)*512)
    int w = threadIdx.x >> 6, lane = threadIdx.x & 63;
    int node = nb * 4 + w;
    int b = node >> 10;
    float* S = nds[w];
    int* J = js[w];
    const float* Pn = P + (size_t)node * NCOLS;
    for (int u = lane; u < 336; u += 64)
        S[u] = (u < 192) ? Pn[u] : Pn[384 + u];           // q | q_pts (cols 576..719)
    if (lane < 32) {
        int j = eidx[node * Kk + lane];
        J[lane] = b * Nn + j;
        S[360 + lane] = ldf(smask, node) * ldf(smask, b * Nn + j);
    } else if (lane < 44) {
        int h = lane - 32;
        float x = ldf(hwq, h);
        S[336 + h] = logf(1.f + expf(x)) * 0.13608276348795434f;   // softplus * sqrt(1/54)
    } else if (lane < 53) {
        int u = lane - 44;
        int i = u / 3, jj = u - i * 3;
        float m = 0;
        #pragma unroll
        for (int l = 0; l < 3; l++)
            m += ldf(rot, node * 9 + l * 3 + i) * ldf(rot, node * 9 + l * 3 + jj);
        S[348 + u] = m;                                    // M = R^T R
    }
    __builtin_amdgcn_wave_barrier();
    // logits + softmax: 6 iterations, (h,k) = (2*it + lane>>5, lane&31)
    #pragma unroll
    for (int it = 0; it < 6; it++) {
        int u = lane + 64 * it;
        int h = u >> 5, k = u & 31;
        const float* Pj = P + (size_t)J[k] * NCOLS;
        float qk = 0;
        const float4* pk4 = (const float4*)(Pj + 192 + h * 16);
        const float4* qs4 = (const float4*)(S + h * 16);
        #pragma unroll
        for (int c4 = 0; c4 < 4; c4++) {
            float4 pv = pk4[c4], qv = qs4[c4];
            qk += qv.x * pv.x + qv.y * pv.y + qv.z * pv.z + qv.w * pv.w;
        }
        float M00 = S[348], M01 = S[349], M02 = S[350],
              M11 = S[352], M12 = S[353], M22 = S[356];
        const float4* pp4 = (const float4*)(Pj + 720 + h * 36);
        const float4* qp4 = (const float4*)(S + 192 + h * 12);
        float4 A0 = pp4[0], A1 = pp4[1], A2 = pp4[2];
        float4 B0 = qp4[0], B1 = qp4[1], B2 = qp4[2];
        float d[12] = {B0.x - A0.x, B0.y - A0.y, B0.z - A0.z, B0.w - A0.w,
                       B1.x - A1.x, B1.y - A1.y, B1.z - A1.z, B1.w - A1.w,
                       B2.x - A2.x, B2.y - A2.y, B2.z - A2.z, B2.w - A2.w};
        float sq = 0;
        #pragma unroll
        for (int p = 0; p < 4; p++) {
            float d0 = d[p * 3], d1 = d[p * 3 + 1], d2 = d[p * 3 + 2];
            sq += M00 * d0 * d0 + M11 * d1 * d1 + M22 * d2 * d2
                + 2.f * (M01 * d0 * d1 + M02 * d0 * d2 + M12 * d1 * d2);
        }
        float logit = qk * 0.14433756729740643f                       // 1/sqrt(48)
                    + 0.5773502691896258f * zout[((size_t)node * Kk + k) * ZOC + h]
                    - 0.5f * S[336 + h] * sq
                    + 1e5f * (S[360 + k] - 1.f);
        float mx = logit;
        #pragma unroll
        for (int m = 16; m; m >>= 1) mx = fmaxf(mx, __shfl_xor(mx, m, 64));
        float e = expf(logit - mx);
        float ssum = e;
        #pragma unroll
        for (int m = 16; m; m >>= 1) ssum += __shfl_xor(ssum, m, 64);
        S[392 + h * 33 + k] = e / ssum;                    // stride-33: bank = (h+k)%32, conflict-free
    }
    __builtin_amdgcn_wave_barrier();
    // accumulation: 216 float4 tasks: o(48) | o_pt raw(72) | o_pair(96)
    for (int u = lane; u < 216; u += 64) {
        int h, off, fbase, pair = 0;
        if (u < 48)       { h = u >> 2; off = 384 + h * 16 + (u & 3) * 4; fbase = h * 16 + (u & 3) * 4; }
        else if (u < 120) { int v = u - 48;  h = v / 6; int q = v - h * 6;
                            off = 732 + h * 36 + q * 4; fbase = 192 + h * 24 + q * 4; }
        else              { int v = u - 120; h = v >> 3;
                            off = 12 + (v & 7) * 4; fbase = 576 + h * 32 + (v & 7) * 4; pair = 1; }
        float4 acc = {0.f, 0.f, 0.f, 0.f};
        const float* lrow = S + 392 + h * 33;
        if (!pair) {
            #pragma unroll 8
            for (int k = 0; k < 32; k++) {
                float lw = lrow[k];
                float4 pv = *(const float4*)(P + (size_t)J[k] * NCOLS + off);
                acc.x += lw * pv.x; acc.y += lw * pv.y; acc.z += lw * pv.z; acc.w += lw * pv.w;
            }
        } else {
            const float* zr = zout + (size_t)node * Kk * ZOC + off;
            #pragma unroll 8
            for (int k = 0; k < 32; k++) {
                float lw = lrow[k];
                float4 pv = *(const float4*)(zr + k * ZOC);
                acc.x += lw * pv.x; acc.y += lw * pv.y; acc.z += lw * pv.z; acc.w += lw * pv.w;
            }
        }
        *(float4*)&S[788 + fbase] = acc;
    }
    __builtin_amdgcn_wave_barrier();
    // apply M to o_pt, compute dists
    for (int u = lane; u < 96; u += 64) {
        float r0 = S[788 + 192 + u * 3 + 0];
        float r1 = S[788 + 192 + u * 3 + 1];
        float r2 = S[788 + 192 + u * 3 + 2];
        float o0 = S[348] * r0 + S[349] * r1 + S[350] * r2;
        float o1 = S[351] * r0 + S[352] * r1 + S[353] * r2;
        float o2 = S[354] * r0 + S[355] * r1 + S[356] * r2;
        S[788 + 192 + u * 3 + 0] = o0;
        S[788 + 192 + u * 3 + 1] = o1;
        S[788 + 192 + u * 3 + 2] = o2;
        S[788 + 480 + u] = sqrtf(o0 * o0 + o1 * o1 + o2 * o2 + 1e-8f);
    }
    __builtin_amdgcn_wave_barrier();
    float* og = featg + (size_t)node * FEAT;
    for (int u = lane; u < 240; u += 64)
        *(float4*)(og + u * 4) = *(const float4*)&S[788 + u * 4];
}

extern "C" void kernel_launch(void* const* d_in, const int* in_sizes, int n_in,
                              void* d_out, int out_size, void* d_ws, size_t ws_size,
                              hipStream_t stream) {
    float* wsf = (float*)d_ws;
    int* flag = (int*)d_ws;
    const void* s = d_in[0];   const void* z = d_in[1];
    const int* eidx = (const int*)d_in[2];
    const void* rot = d_in[3];                         // d_in[4] trans: unused (cancels exactly)
    const void* smask = d_in[5];
    const void* lns_sc = d_in[6]; const void* lns_bi = d_in[7];
    const void* lnz_sc = d_in[8]; const void* lnz_bi = d_in[9];
    const void* wq = d_in[10]; const void* wk = d_in[11]; const void* wv = d_in[12];
    const void* wqp = d_in[13]; const void* wkvp = d_in[14];
    const void* wb = d_in[15]; const void* wdz = d_in[16];
    const void* hwq = d_in[17]; const void* wout = d_in[18];

    // Host-side dtype resolution from byte size of s (4096*384 elements).
    int mode = -1;  // 0 = f32, 1 = bf16, -1 = unknown -> guarded dual launch
    if (in_sizes) {
        if (in_sizes[0] == NNODE * CS * 4) mode = 0;
        else if (in_sizes[0] == NNODE * CS * 2) mode = 1;
    }

    const int* fg = (mode < 0) ? flag : nullptr;   // null => unguarded
    if (mode < 0) k_detect<<<1, 64, 0, stream>>>((const unsigned*)smask, flag);

    #define LAUNCH_T(T, WANT)                                                                     \
        do {                                                                                      \
            k_prep<T><<<2112 + 4096 + 1, 384, 0, stream>>>((const T*)s, (const T*)lns_sc,         \
                (const T*)lns_bi, (const T*)wq, (const T*)wk, (const T*)wv, (const T*)wqp,        \
                (const T*)wkvp, (const T*)wout, (const T*)wb, (const T*)wdz, (const T*)lnz_sc,    \
                (const T*)lnz_bi, wsf, fg, WANT);                                                 \
            k_zg<T><<<NEDGE / 256, 256, 0, stream>>>((const T*)z, wsf + O_WZP, wsf + O_BVEC,      \
                wsf + O_CSUM, wsf + O_ZOUT, fg, WANT);                                            \
        } while (0)

    #define LAUNCH_ATTN(T, WANT)                                                                  \
        k_attn<T><<<NNODE / 4, 256, 0, stream>>>(wsf + O_P, wsf + O_ZOUT, eidx,                   \
            (const T*)smask, (const T*)rot, (const T*)hwq, wsf + O_FEAT, fg, WANT)

    if (mode == 0) {
        LAUNCH_T(float, 0);
    } else if (mode == 1) {
        LAUNCH_T(__hip_bfloat16, 1);
    } else {
        LAUNCH_T(float, 0);
        LAUNCH_T(__hip_bfloat16, 1);
    }

    // P = s_ln @ [w_q|w_k|w_v|w_q_pts|w_kv_pts]   (f32, dtype-independent)
    k_gemm<<<dim3(NNODE / 64, NCOLS / 128), 256, 0, stream>>>(
        wsf + O_SLN, CS, wsf + O_WNODE, NCOLS, wsf + O_P, NCOLS, CS);

    if (mode == 0) {
        LAUNCH_ATTN(float, 0);
        k_gout<float><<<dim3(NNODE / 32, CS / 64), 256, 0, stream>>>(
            wsf + O_FEAT, wsf + O_WOUT, (float*)d_out, fg, 0);
    } else if (mode == 1) {
        LAUNCH_ATTN(__hip_bfloat16, 1);
        k_gout<__hip_bfloat16><<<dim3(NNODE / 32, CS / 64), 256, 0, stream>>>(
            wsf + O_FEAT, wsf + O_WOUT, (__hip_bfloat16*)d_out, fg, 1);
    } else {
        LAUNCH_ATTN(float, 0);
        LAUNCH_ATTN(__hip_bfloat16, 1);
        k_gout<float><<<dim3(NNODE / 32, CS / 64), 256, 0, stream>>>(
            wsf + O_FEAT, wsf + O_WOUT, (float*)d_out, fg, 0);
        k_gout<__hip_bfloat16><<<dim3(NNODE / 32, CS / 64), 256, 0, stream>>>(
            wsf + O_FEAT, wsf + O_WOUT, (__hip_bfloat16*)d_out, fg, 1);
    }
    #undef LAUNCH_T
    #undef LAUNCH_ATTN
}

// Round 5
// 345.915 us; speedup vs baseline: 1.4125x; 1.0889x over previous
//
#include <hip/hip_runtime.h>
#include <hip/hip_bf16.h>

// Problem constants
constexpr int Bb = 4, Nn = 1024, Kk = 32;
constexpr int CS = 384, CZ = 128, CH = 16, Hh = 12, PQn = 4, PVn = 8;
constexpr int NCOLS = 1152;            // q(192)|k(192)|v(192)|qp(144)|kvp(432)
constexpr int FEAT = 960;              // o(192)|o_pt(288)|dists(96)|o_pair(384)
constexpr int NNODE = Bb * Nn;         // 4096
constexpr int NEDGE = NNODE * Kk;      // 131072
constexpr int ZOC = 44;                // zout cols: bbuf(12) | zd(32)

// Workspace float offsets (flag occupies wsf[0..3]).  All offsets divisible by 4 (16B align).
constexpr int O_WZP   = 4;                            // [128][48] LN-scale-folded [wb|wdz]
constexpr int O_BVEC  = O_WZP + 6144;                 // [48]
constexpr int O_CSUM  = O_BVEC + 48;                  // [48]
constexpr int O_P     = O_CSUM + 48;                  // [4096][1152] f32
constexpr int O_ZOUT  = O_P + NNODE * NCOLS;          // [131072][44] f32
constexpr int O_SLNH  = O_ZOUT + NEDGE * ZOC;         // [4096][384] ushort (bf16 hi)
constexpr int O_SLNL  = O_SLNH + NNODE * CS / 2;      // [4096][384] ushort (bf16 lo)
constexpr int O_WNTH  = O_SLNL + NNODE * CS / 2;      // [1152][384] ushort (W_node^T hi)
constexpr int O_WNTL  = O_WNTH + NCOLS * CS / 2;      // [1152][384] ushort
constexpr int O_WOTH  = O_WNTL + NCOLS * CS / 2;      // [384][960] ushort (w_out^T hi)
constexpr int O_WOTL  = O_WOTH + CS * FEAT / 2;       // [384][960] ushort
// feat hi aliases sln/wnodeT (dead after P-GEMM): spans 1.97M < 2.01M available
constexpr int O_FEATH = O_SLNH;                       // [4096][960] ushort
constexpr int O_FEATL = O_WOTL + CS * FEAT / 2;       // [4096][960] ushort
constexpr int TOTAL_F = O_FEATL + NNODE * FEAT / 2;   // ~14.84M floats = 59.4 MB

typedef __attribute__((ext_vector_type(8)))  short short8x;
typedef __attribute__((ext_vector_type(16))) float f32x16;

__device__ __forceinline__ float ldf(const float* p, int i) { return p[i]; }
__device__ __forceinline__ float ldf(const __hip_bfloat16* p, int i) { return __bfloat162float(p[i]); }
__device__ __forceinline__ void stf(float* p, size_t i, float v) { p[i] = v; }
__device__ __forceinline__ void stf(__hip_bfloat16* p, size_t i, float v) { p[i] = __float2bfloat16(v); }
__device__ __forceinline__ float4 ld4(const float* p, int i) { return *(const float4*)(p + i); }
__device__ __forceinline__ float4 ld4(const __hip_bfloat16* p, int i) {
    ushort4 u = *(const ushort4*)(p + i);
    return make_float4(__uint_as_float((unsigned)u.x << 16),
                       __uint_as_float((unsigned)u.y << 16),
                       __uint_as_float((unsigned)u.z << 16),
                       __uint_as_float((unsigned)u.w << 16));
}
// Split f32 -> bf16 hi (truncate) + bf16 lo (residual, truncate). Residual exact in f32.
__device__ __forceinline__ void split_bf(float v, unsigned short& h, unsigned short& l) {
    h = (unsigned short)(__float_as_uint(v) >> 16);
    float r = v - __uint_as_float((unsigned)h << 16);
    l = (unsigned short)(__float_as_uint(r) >> 16);
}

// Fallback dtype detect from s_mask (all ones): f32 -> 0x3F800000, bf16x2 -> 0x3F803F80
__global__ void k_detect(const unsigned* smask_raw, int* flag) {
    if (threadIdx.x == 0) *flag = (smask_raw[0] == 0x3F803F80u) ? 1 : 0;
}

// Fused prep:
//  blocks [0,1152):     wnodeT hi/lo  (block = out column n, threads over k)
//  blocks [1152,1536):  woutT hi/lo   (block = out column n, threads loop k)
//  blocks [1536,5632):  s LayerNorm -> sln hi/lo
//  block  5632:         z-weight prep (W' = diag(zsc)@[wb|wdz], bvec, csum)
template <typename T>
__global__ __launch_bounds__(384) void k_prep(const T* s, const T* lns_sc, const T* lns_bi,
                                              const T* wq, const T* wk, const T* wv,
                                              const T* wqp, const T* wkvp, const T* wout,
                                              const T* wb, const T* wdz, const T* zsc, const T* zbi,
                                              float* wsf, const int* flag, int want) {
    if (flag && *flag != want) return;
    int blk = blockIdx.x, t = threadIdx.x;
    unsigned short* wntH = (unsigned short*)(wsf + O_WNTH);
    unsigned short* wntL = (unsigned short*)(wsf + O_WNTL);
    unsigned short* wotH = (unsigned short*)(wsf + O_WOTH);
    unsigned short* wotL = (unsigned short*)(wsf + O_WOTL);
    unsigned short* slnH = (unsigned short*)(wsf + O_SLNH);
    unsigned short* slnL = (unsigned short*)(wsf + O_SLNL);
    __shared__ float ssum[6], ssq[6];
    if (blk < 1152) {
        int n = blk, k = t;
        float v;
        if      (n < 192) v = ldf(wq,  k * 192 + n);
        else if (n < 384) v = ldf(wk,  k * 192 + n - 192);
        else if (n < 576) v = ldf(wv,  k * 192 + n - 384);
        else if (n < 720) v = ldf(wqp, k * 144 + n - 576);
        else              v = ldf(wkvp, k * 432 + n - 720);
        unsigned short h, l; split_bf(v, h, l);
        wntH[n * 384 + k] = h; wntL[n * 384 + k] = l;
    } else if (blk < 1536) {
        int n = blk - 1152;
        for (int k = t; k < 960; k += 384) {
            float v = ldf(wout, k * 384 + n);
            unsigned short h, l; split_bf(v, h, l);
            wotH[n * 960 + k] = h; wotL[n * 960 + k] = l;
        }
    } else if (blk < 1536 + 4096) {
        int row = blk - 1536;
        float x = ldf(s, row * CS + t);
        float sum = x, sq = x * x;
        #pragma unroll
        for (int m = 32; m; m >>= 1) { sum += __shfl_xor(sum, m, 64); sq += __shfl_xor(sq, m, 64); }
        int w = t >> 6;
        if ((t & 63) == 0) { ssum[w] = sum; ssq[w] = sq; }
        __syncthreads();
        if (t == 0) {
            float S = 0, Q = 0;
            for (int i = 0; i < 6; i++) { S += ssum[i]; Q += ssq[i]; }
            ssum[0] = S; ssq[0] = Q;
        }
        __syncthreads();
        float mean = ssum[0] * (1.f / CS);
        float var  = ssq[0] * (1.f / CS) - mean * mean;
        float r = rsqrtf(var + 1e-5f);
        float y = (x - mean) * r * ldf(lns_sc, t) + ldf(lns_bi, t);
        unsigned short h, l; split_bf(y, h, l);
        slnH[row * CS + t] = h; slnL[row * CS + t] = l;
    } else {
        if (t < 128) {
            float sc = ldf(zsc, t);
            for (int o = 0; o < 48; o++) {
                float w = 0.f;
                if (o < 12)      w = ldf(wb, t * 12 + o);
                else if (o < 44) w = ldf(wdz, t * 32 + o - 12);
                wsf[O_WZP + t * 48 + o] = sc * w;
            }
        } else if (t < 176) {
            int o = t - 128;
            float acc = 0.f;
            if (o < 44)
                for (int c = 0; c < 128; c++)
                    acc += ldf(zbi, c) * (o < 12 ? ldf(wb, c * 12 + o) : ldf(wdz, c * 32 + o - 12));
            wsf[O_BVEC + o] = acc;
        } else if (t < 224) {
            int o = t - 176;
            float acc = 0.f;
            if (o < 44)
                for (int c = 0; c < 128; c++)
                    acc += ldf(zsc, c) * (o < 12 ? ldf(wb, c * 12 + o) : ldf(wdz, c * 32 + o - 12));
            wsf[O_CSUM + o] = acc;
        }
    }
}

// z-GEMM with fused LN: accumulate RAW z @ W', per-row stats in-flight,
// epilogue: zout = rs*acc - rs*mu*csum + bvec.  256 edges/block.
template <typename T>
__global__ __launch_bounds__(256) void k_zg(const T* z, const float* wzp, const float* bvec,
                                            const float* csum, float* zout,
                                            const int* flag, int want) {
    if (flag && *flag != want) return;
    __shared__ float Ws[128 * 48];
    __shared__ float As[16][260];
    __shared__ float mus[256], rss[256];
    int t = threadIdx.x;
    int edge0 = blockIdx.x * 256;
    for (int i = t; i < 128 * 48; i += 256) Ws[i] = wzp[i];
    int tm = t >> 2, tn = t & 3, col = tn * 12;
    int sr = t >> 2, q = t & 3;
    float psum[4] = {}, psq[4] = {};
    float acc[4][12] = {};
    for (int kt = 0; kt < CZ; kt += 16) {
        float4 zv[4];
        #pragma unroll
        for (int u = 0; u < 4; u++) {
            zv[u] = ld4(z, (edge0 + sr + 64 * u) * CZ + kt + q * 4);
            psum[u] += zv[u].x + zv[u].y + zv[u].z + zv[u].w;
            psq[u]  += zv[u].x * zv[u].x + zv[u].y * zv[u].y
                     + zv[u].z * zv[u].z + zv[u].w * zv[u].w;
        }
        __syncthreads();
        #pragma unroll
        for (int u = 0; u < 4; u++) {
            int rr = sr + 64 * u;
            As[q * 4 + 0][rr] = zv[u].x;
            As[q * 4 + 1][rr] = zv[u].y;
            As[q * 4 + 2][rr] = zv[u].z;
            As[q * 4 + 3][rr] = zv[u].w;
        }
        __syncthreads();
        #pragma unroll
        for (int kk = 0; kk < 16; kk++) {
            float4 a = *(const float4*)&As[kk][tm * 4];
            const float* wr = &Ws[(kt + kk) * 48 + col];
            float4 b0 = *(const float4*)(wr);
            float4 b1 = *(const float4*)(wr + 4);
            float4 b2 = *(const float4*)(wr + 8);
            float av[4]  = {a.x, a.y, a.z, a.w};
            float bv[12] = {b0.x, b0.y, b0.z, b0.w, b1.x, b1.y, b1.z, b1.w, b2.x, b2.y, b2.z, b2.w};
            #pragma unroll
            for (int i = 0; i < 4; i++)
                #pragma unroll
                for (int j = 0; j < 12; j++) acc[i][j] += av[i] * bv[j];
        }
        __syncthreads();
    }
    #pragma unroll
    for (int u = 0; u < 4; u++) {
        float s = psum[u], qq = psq[u];
        s += __shfl_xor(s, 1, 64); s += __shfl_xor(s, 2, 64);
        qq += __shfl_xor(qq, 1, 64); qq += __shfl_xor(qq, 2, 64);
        if (q == 0) {
            float mu = s * (1.f / CZ);
            mus[sr + 64 * u] = mu;
            rss[sr + 64 * u] = rsqrtf(qq * (1.f / CZ) - mu * mu + 1e-5f);
        }
    }
    __syncthreads();
    #pragma unroll
    for (int i = 0; i < 4; i++) {
        int r = tm * 4 + i;
        float mu = mus[r], rs = rss[r];
        int e = edge0 + r;
        #pragma unroll
        for (int j = 0; j < 12; j++) {
            int c = col + j;
            if (c < ZOC) zout[(size_t)e * ZOC + c] = rs * acc[i][j] - rs * mu * csum[c] + bvec[c];
        }
    }
}

// Split-bf16 MFMA GEMM: C = A*B where A=[M][K] hi/lo bf16 row-major, B^T=[N][K] hi/lo bf16.
// 64x64 tile per 1-wave block, no LDS, no barriers; frags from L2; reg prefetch 1 K-step ahead.
// 3 MFMAs per product: Ah*Bh + Ah*Bl + Al*Bh  (err ~2^-16 rel).
#define MFMA3(C, AH, AL, BH, BL)                                              \
    C = __builtin_amdgcn_mfma_f32_32x32x16_bf16(AH, BH, C, 0, 0, 0);          \
    C = __builtin_amdgcn_mfma_f32_32x32x16_bf16(AH, BL, C, 0, 0, 0);          \
    C = __builtin_amdgcn_mfma_f32_32x32x16_bf16(AL, BH, C, 0, 0, 0);

template <typename TO>
__global__ __launch_bounds__(64) void k_mgemm(const unsigned short* AH, const unsigned short* AL,
                                              int lda, const unsigned short* BH,
                                              const unsigned short* BL, int ldb,
                                              TO* C, int ldc, int Kdim,
                                              const int* flag, int want) {
    if (flag && *flag != want) return;
    int l = threadIdx.x, r = l & 31, g = l >> 5;
    size_t a0 = (size_t)(blockIdx.x * 64 + r) * lda + 8 * g;
    size_t a1 = a0 + (size_t)32 * lda;
    size_t b0 = (size_t)(blockIdx.y * 64 + r) * ldb + 8 * g;
    size_t b1 = b0 + (size_t)32 * ldb;
    f32x16 c00 = {}, c01 = {}, c10 = {}, c11 = {};
    short8x aH0 = *(const short8x*)(AH + a0), aH1 = *(const short8x*)(AH + a1);
    short8x aL0 = *(const short8x*)(AL + a0), aL1 = *(const short8x*)(AL + a1);
    short8x bH0 = *(const short8x*)(BH + b0), bH1 = *(const short8x*)(BH + b1);
    short8x bL0 = *(const short8x*)(BL + b0), bL1 = *(const short8x*)(BL + b1);
    for (int kt = 0; kt < Kdim; kt += 16) {
        int kn = (kt + 16 < Kdim) ? kt + 16 : 0;   // last-iter prefetch is dummy (safe, unused)
        short8x nAH0 = *(const short8x*)(AH + a0 + kn), nAH1 = *(const short8x*)(AH + a1 + kn);
        short8x nAL0 = *(const short8x*)(AL + a0 + kn), nAL1 = *(const short8x*)(AL + a1 + kn);
        short8x nBH0 = *(const short8x*)(BH + b0 + kn), nBH1 = *(const short8x*)(BH + b1 + kn);
        short8x nBL0 = *(const short8x*)(BL + b0 + kn), nBL1 = *(const short8x*)(BL + b1 + kn);
        MFMA3(c00, aH0, aL0, bH0, bL0)
        MFMA3(c01, aH0, aL0, bH1, bL1)
        MFMA3(c10, aH1, aL1, bH0, bL0)
        MFMA3(c11, aH1, aL1, bH1, bL1)
        aH0 = nAH0; aH1 = nAH1; aL0 = nAL0; aL1 = nAL1;
        bH0 = nBH0; bH1 = nBH1; bL0 = nBL0; bL1 = nBL1;
    }
    // D layout: col = lane&31, row = (reg&3) + 8*(reg>>2) + 4*(lane>>5)
    #pragma unroll
    for (int reg = 0; reg < 16; reg++) {
        int row = (reg & 3) + 8 * (reg >> 2) + 4 * g;
        size_t rm = (size_t)(blockIdx.x * 64 + row);
        int cn = blockIdx.y * 64 + r;
        stf(C, rm * ldc + cn,               c00[reg]);
        stf(C, rm * ldc + cn + 32,          c01[reg]);
        stf(C, (rm + 32) * ldc + cn,        c10[reg]);
        stf(C, (rm + 32) * ldc + cn + 32,   c11[reg]);
    }
}

// Attention: one wave per node, XCD-chunked swizzle, stride-33 softmax array.
// Per-node LDS (1760 f32): q[0..192) qp[192..336) hw[336..348) Mn[348..357) msk[360..392)
//                          l[392..788) stride-33 | feat[788..1748)
template <typename T>
__global__ __launch_bounds__(256) void k_attn(const float* P, const float* zout,
                                              const int* eidx, const T* smask, const T* rot,
                                              const T* hwq, unsigned short* featH,
                                              unsigned short* featL, const int* flag, int want) {
    if (flag && *flag != want) return;
    __shared__ float nds[4][1760];
    __shared__ int js[4][32];
    int bid = blockIdx.x;
    int nb = ((bid & 7) << 7) + (bid >> 3);   // XCD-chunked
    int w = threadIdx.x >> 6, lane = threadIdx.x & 63;
    int node = nb * 4 + w;
    int b = node >> 10;
    float* S = nds[w];
    int* J = js[w];
    const float* Pn = P + (size_t)node * NCOLS;
    for (int u = lane; u < 336; u += 64)
        S[u] = (u < 192) ? Pn[u] : Pn[384 + u];           // q | q_pts (cols 576..719)
    if (lane < 32) {
        int j = eidx[node * Kk + lane];
        J[lane] = b * Nn + j;
        S[360 + lane] = ldf(smask, node) * ldf(smask, b * Nn + j);
    } else if (lane < 44) {
        int h = lane - 32;
        float x = ldf(hwq, h);
        S[336 + h] = logf(1.f + expf(x)) * 0.13608276348795434f;   // softplus * sqrt(1/54)
    } else if (lane < 53) {
        int u = lane - 44;
        int i = u / 3, jj = u - i * 3;
        float m = 0;
        #pragma unroll
        for (int l = 0; l < 3; l++)
            m += ldf(rot, node * 9 + l * 3 + i) * ldf(rot, node * 9 + l * 3 + jj);
        S[348 + u] = m;                                    // M = R^T R
    }
    __builtin_amdgcn_wave_barrier();
    #pragma unroll
    for (int it = 0; it < 6; it++) {
        int u = lane + 64 * it;
        int h = u >> 5, k = u & 31;
        const float* Pj = P + (size_t)J[k] * NCOLS;
        float qk = 0;
        const float4* pk4 = (const float4*)(Pj + 192 + h * 16);
        const float4* qs4 = (const float4*)(S + h * 16);
        #pragma unroll
        for (int c4 = 0; c4 < 4; c4++) {
            float4 pv = pk4[c4], qv = qs4[c4];
            qk += qv.x * pv.x + qv.y * pv.y + qv.z * pv.z + qv.w * pv.w;
        }
        float M00 = S[348], M01 = S[349], M02 = S[350],
              M11 = S[352], M12 = S[353], M22 = S[356];
        const float4* pp4 = (const float4*)(Pj + 720 + h * 36);
        const float4* qp4 = (const float4*)(S + 192 + h * 12);
        float4 A0 = pp4[0], A1 = pp4[1], A2 = pp4[2];
        float4 B0 = qp4[0], B1 = qp4[1], B2 = qp4[2];
        float d[12] = {B0.x - A0.x, B0.y - A0.y, B0.z - A0.z, B0.w - A0.w,
                       B1.x - A1.x, B1.y - A1.y, B1.z - A1.z, B1.w - A1.w,
                       B2.x - A2.x, B2.y - A2.y, B2.z - A2.z, B2.w - A2.w};
        float sq = 0;
        #pragma unroll
        for (int p = 0; p < 4; p++) {
            float d0 = d[p * 3], d1 = d[p * 3 + 1], d2 = d[p * 3 + 2];
            sq += M00 * d0 * d0 + M11 * d1 * d1 + M22 * d2 * d2
                + 2.f * (M01 * d0 * d1 + M02 * d0 * d2 + M12 * d1 * d2);
        }
        float logit = qk * 0.14433756729740643f
                    + 0.5773502691896258f * zout[((size_t)node * Kk + k) * ZOC + h]
                    - 0.5f * S[336 + h] * sq
                    + 1e5f * (S[360 + k] - 1.f);
        float mx = logit;
        #pragma unroll
        for (int m = 16; m; m >>= 1) mx = fmaxf(mx, __shfl_xor(mx, m, 64));
        float e = expf(logit - mx);
        float ssum = e;
        #pragma unroll
        for (int m = 16; m; m >>= 1) ssum += __shfl_xor(ssum, m, 64);
        S[392 + h * 33 + k] = e / ssum;
    }
    __builtin_amdgcn_wave_barrier();
    for (int u = lane; u < 216; u += 64) {
        int h, off, fbase, pair = 0;
        if (u < 48)       { h = u >> 2; off = 384 + h * 16 + (u & 3) * 4; fbase = h * 16 + (u & 3) * 4; }
        else if (u < 120) { int v = u - 48;  h = v / 6; int q = v - h * 6;
                            off = 732 + h * 36 + q * 4; fbase = 192 + h * 24 + q * 4; }
        else              { int v = u - 120; h = v >> 3;
                            off = 12 + (v & 7) * 4; fbase = 576 + h * 32 + (v & 7) * 4; pair = 1; }
        float4 acc = {0.f, 0.f, 0.f, 0.f};
        const float* lrow = S + 392 + h * 33;
        if (!pair) {
            #pragma unroll 8
            for (int k = 0; k < 32; k++) {
                float lw = lrow[k];
                float4 pv = *(const float4*)(P + (size_t)J[k] * NCOLS + off);
                acc.x += lw * pv.x; acc.y += lw * pv.y; acc.z += lw * pv.z; acc.w += lw * pv.w;
            }
        } else {
            const float* zr = zout + (size_t)node * Kk * ZOC + off;
            #pragma unroll 8
            for (int k = 0; k < 32; k++) {
                float lw = lrow[k];
                float4 pv = *(const float4*)(zr + k * ZOC);
                acc.x += lw * pv.x; acc.y += lw * pv.y; acc.z += lw * pv.z; acc.w += lw * pv.w;
            }
        }
        *(float4*)&S[788 + fbase] = acc;
    }
    __builtin_amdgcn_wave_barrier();
    for (int u = lane; u < 96; u += 64) {
        float r0 = S[788 + 192 + u * 3 + 0];
        float r1 = S[788 + 192 + u * 3 + 1];
        float r2 = S[788 + 192 + u * 3 + 2];
        float o0 = S[348] * r0 + S[349] * r1 + S[350] * r2;
        float o1 = S[351] * r0 + S[352] * r1 + S[353] * r2;
        float o2 = S[354] * r0 + S[355] * r1 + S[356] * r2;
        S[788 + 192 + u * 3 + 0] = o0;
        S[788 + 192 + u * 3 + 1] = o1;
        S[788 + 192 + u * 3 + 2] = o2;
        S[788 + 480 + u] = sqrtf(o0 * o0 + o1 * o1 + o2 * o2 + 1e-8f);
    }
    __builtin_amdgcn_wave_barrier();
    for (int u = lane; u < FEAT; u += 64) {
        unsigned short h, l; split_bf(S[788 + u], h, l);
        featH[(size_t)node * FEAT + u] = h;
        featL[(size_t)node * FEAT + u] = l;
    }
}

extern "C" void kernel_launch(void* const* d_in, const int* in_sizes, int n_in,
                              void* d_out, int out_size, void* d_ws, size_t ws_size,
                              hipStream_t stream) {
    float* wsf = (float*)d_ws;
    int* flag = (int*)d_ws;
    const void* s = d_in[0];   const void* z = d_in[1];
    const int* eidx = (const int*)d_in[2];
    const void* rot = d_in[3];                         // d_in[4] trans: unused (cancels exactly)
    const void* smask = d_in[5];
    const void* lns_sc = d_in[6]; const void* lns_bi = d_in[7];
    const void* lnz_sc = d_in[8]; const void* lnz_bi = d_in[9];
    const void* wq = d_in[10]; const void* wk = d_in[11]; const void* wv = d_in[12];
    const void* wqp = d_in[13]; const void* wkvp = d_in[14];
    const void* wb = d_in[15]; const void* wdz = d_in[16];
    const void* hwq = d_in[17]; const void* wout = d_in[18];

    unsigned short* slnH = (unsigned short*)(wsf + O_SLNH);
    unsigned short* slnL = (unsigned short*)(wsf + O_SLNL);
    unsigned short* wntH = (unsigned short*)(wsf + O_WNTH);
    unsigned short* wntL = (unsigned short*)(wsf + O_WNTL);
    unsigned short* wotH = (unsigned short*)(wsf + O_WOTH);
    unsigned short* wotL = (unsigned short*)(wsf + O_WOTL);
    unsigned short* featH = (unsigned short*)(wsf + O_FEATH);
    unsigned short* featL = (unsigned short*)(wsf + O_FEATL);

    int mode = -1;  // 0 = f32, 1 = bf16, -1 = unknown -> guarded dual launch
    if (in_sizes) {
        if (in_sizes[0] == NNODE * CS * 4) mode = 0;
        else if (in_sizes[0] == NNODE * CS * 2) mode = 1;
    }
    const int* fg = (mode < 0) ? flag : nullptr;
    if (mode < 0) k_detect<<<1, 64, 0, stream>>>((const unsigned*)smask, flag);

    #define LAUNCH_FRONT(T, WANT)                                                                 \
        do {                                                                                      \
            k_prep<T><<<5633, 384, 0, stream>>>((const T*)s, (const T*)lns_sc, (const T*)lns_bi,  \
                (const T*)wq, (const T*)wk, (const T*)wv, (const T*)wqp, (const T*)wkvp,          \
                (const T*)wout, (const T*)wb, (const T*)wdz, (const T*)lnz_sc, (const T*)lnz_bi,  \
                wsf, fg, WANT);                                                                   \
            k_zg<T><<<NEDGE / 256, 256, 0, stream>>>((const T*)z, wsf + O_WZP, wsf + O_BVEC,      \
                wsf + O_CSUM, wsf + O_ZOUT, fg, WANT);                                            \
        } while (0)

    #define LAUNCH_ATTN(T, WANT)                                                                  \
        k_attn<T><<<NNODE / 4, 256, 0, stream>>>(wsf + O_P, wsf + O_ZOUT, eidx,                   \
            (const T*)smask, (const T*)rot, (const T*)hwq, featH, featL, fg, WANT)

    if (mode == 0)      LAUNCH_FRONT(float, 0);
    else if (mode == 1) LAUNCH_FRONT(__hip_bfloat16, 1);
    else { LAUNCH_FRONT(float, 0); LAUNCH_FRONT(__hip_bfloat16, 1); }

    // P = s_ln @ W_node  (MFMA split-bf16; dtype-independent)
    k_mgemm<float><<<dim3(NNODE / 64, NCOLS / 64), 64, 0, stream>>>(
        slnH, slnL, CS, wntH, wntL, CS, wsf + O_P, NCOLS, CS, nullptr, 0);

    if (mode == 0) {
        LAUNCH_ATTN(float, 0);
        k_mgemm<float><<<dim3(NNODE / 64, CS / 64), 64, 0, stream>>>(
            featH, featL, FEAT, wotH, wotL, FEAT, (float*)d_out, CS, FEAT, nullptr, 0);
    } else if (mode == 1) {
        LAUNCH_ATTN(__hip_bfloat16, 1);
        k_mgemm<__hip_bfloat16><<<dim3(NNODE / 64, CS / 64), 64, 0, stream>>>(
            featH, featL, FEAT, wotH, wotL, FEAT, (__hip_bfloat16*)d_out, CS, FEAT, nullptr, 0);
    } else {
        LAUNCH_ATTN(float, 0);
        LAUNCH_ATTN(__hip_bfloat16, 1);
        k_mgemm<float><<<dim3(NNODE / 64, CS / 64), 64, 0, stream>>>(
            featH, featL, FEAT, wotH, wotL, FEAT, (float*)d_out, CS, FEAT, fg, 0);
        k_mgemm<__hip_bfloat16><<<dim3(NNODE / 64, CS / 64), 64, 0, stream>>>(
            featH, featL, FEAT, wotH, wotL, FEAT, (__hip_bfloat16*)d_out, CS, FEAT, fg, 1);
    }
    #undef LAUNCH_FRONT
    #undef LAUNCH_ATTN
}